// Round 17
// baseline (2662.001 us; speedup 1.0000x reference)
//
#include <hip/hip_runtime.h>
#include <hip/hip_bf16.h>
#include <cstdint>
#include <cstddef>

namespace {
constexpr int T_ = 500, S_ = 32, B_ = 128, L_ = 64, R_ = 8;

typedef __attribute__((ext_vector_type(8))) short short8;
typedef __attribute__((ext_vector_type(4))) float f32x4;

__device__ __forceinline__ float rdlane(float v, int l) {
  return __int_as_float(__builtin_amdgcn_readlane(__float_as_int(v), l));
}
template<int CTRL, int RM>
__device__ __forceinline__ float dppadd(float v) {
  int t = __builtin_amdgcn_update_dpp(0, __float_as_int(v), CTRL, RM, 0xf, false);
  return v + __int_as_float(t);
}
__device__ __forceinline__ float wredsum(float v) {
  v = dppadd<0x111, 0xf>(v);
  v = dppadd<0x112, 0xf>(v);
  v = dppadd<0x114, 0xf>(v);
  v = dppadd<0x118, 0xf>(v);
  v = dppadd<0x142, 0xa>(v);
  v = dppadd<0x143, 0xc>(v);
  return v;
}
__device__ __forceinline__ float wsum(float v) {
  v += __shfl_xor(v, 1);  v += __shfl_xor(v, 2);  v += __shfl_xor(v, 4);
  v += __shfl_xor(v, 8);  v += __shfl_xor(v, 16); v += __shfl_xor(v, 32);
  return v;
}
__device__ __forceinline__ void gload16(const float* g, float* l) {
  __builtin_amdgcn_global_load_lds((const __attribute__((address_space(1))) uint32_t*)g,
                                   (__attribute__((address_space(3))) uint32_t*)l,
                                   16, 0, 0);
}
// barrier draining LDS only (global loads stay in flight)
__device__ __forceinline__ void bar_lgkm() {
  asm volatile("s_waitcnt lgkmcnt(0)\n\ts_barrier" ::: "memory");
}
// barrier draining LDS + all vector-memory (fences the async prefetches)
__device__ __forceinline__ void barV() {
  asm volatile("s_waitcnt vmcnt(0) lgkmcnt(0)\n\ts_barrier" ::: "memory");
}
// truncation split: v ~= hi + lo, rel err ~2^-16, ~4 VALU ops/element.
__device__ __forceinline__ void fsplit(const float (&v)[8], short8& hi, short8& lo) {
#pragma unroll
  for (int j = 0; j < 8; ++j) {
    uint32_t u = __float_as_uint(v[j]);
    hi[j] = (short)(u >> 16);
    float hf = __uint_as_float(u & 0xFFFF0000u);
    float lf = v[j] - hf;
    lo[j] = (short)(__float_as_uint(lf) >> 16);
  }
}
__device__ __forceinline__ void ldfragF(const float* p, short8& hi, short8& lo) {
  float4 a = *(const float4*)p, b = *(const float4*)(p + 4);
  float v[8] = {a.x,a.y,a.z,a.w,b.x,b.y,b.z,b.w};
  fsplit(v, hi, lo);
}
__device__ __forceinline__ f32x4 mfma3(short8 ah, short8 al, short8 bh, short8 bl,
                                       f32x4 acc) {
  acc = __builtin_amdgcn_mfma_f32_16x16x32_bf16(ah, bh, acc, 0, 0, 0);
  acc = __builtin_amdgcn_mfma_f32_16x16x32_bf16(al, bh, acc, 0, 0, 0);
  acc = __builtin_amdgcn_mfma_f32_16x16x32_bf16(ah, bl, acc, 0, 0, 0);
  return acc;
}
}  // namespace

// One block per batch element b. 512 threads = 8 waves, 4 ensemble rows/wave.
// R16 structure; this round: W8 = (MKM + diag(q)K) @ inv(C8) computed ONCE by
// wave 1 (mkm -> Gram -> Cholesky FACTOR -> 64 per-lane triangular solves via
// rdlane broadcasts) and published as W8_s[64][8]. P4's per-wave M8 fold
// (16 b128 + 128 FMA each) collapses to one 2-b128 W8-row read + 8 FMA/row.
// M8/chol8M8 retained for step 0 only.
__global__ __launch_bounds__(512, 1) void nlf_kernel(
    const float* __restrict__ m0p, const float* __restrict__ q0p,
    const float* __restrict__ qp,  const float* __restrict__ kp,
    const float* __restrict__ Kp,  const float* __restrict__ Ap,
    const float* __restrict__ wp0p, const float* __restrict__ wf0p,
    const float* __restrict__ wp1p, const float* __restrict__ wp2p,
    const float* __restrict__ wfp,  float* __restrict__ outp)
{
  __shared__ __align__(16) float z_s[S_*68];      // carry z' (z - mf)
  __shared__ __align__(16) float zn_s[S_*68];     // zn (P1->P2), then zp (P3a->P4)
  __shared__ __align__(16) float Mc_s[L_*36];     // M_c fp32 (w0 mctk, w1 mkm)
  __shared__ __align__(16) short McH_s[L_*40];    // M_c hi, l-major
  __shared__ __align__(16) short McL_s[L_*40];    // M_c lo
  __shared__ __align__(16) short McTH_s[S_*72];   // M_c hi, s-major
  __shared__ __align__(16) short McTL_s[S_*72];
  __shared__ __align__(16) short KtTH_s[R_*72];   // K^T hi, r-major
  __shared__ __align__(16) short KtTL_s[R_*72];
  __shared__ __align__(16) float uni[8*68];       // mp partials
  __shared__ __align__(16) float wp1b[2][S_*S_];
  __shared__ __align__(16) float wp2b[2][S_*L_];
  __shared__ __align__(16) float wfb[2][S_*R_];   // wf double-buffer
  __shared__ __align__(16) float Ktb[2][L_*R_];   // K double-buffer (l-major)
  __shared__ __align__(16) float KtT_s[R_*68];    // K^T fp32 (w1 C8 q-Gram)
  __shared__ __align__(16) float ktv_s[L_];       // k_t vector
  __shared__ __align__(16) float v1t_s[S_*R_];
  __shared__ __align__(16) float KM_s[S_*R_];     // (Mc^T K)[s][r]
  __shared__ __align__(16) float KMT_s[R_*36];    // (Mc^T K)^T [r][s]
  __shared__ __align__(16) float W8_s[L_*R_];     // W8[l][r] (w1 -> all)
  __shared__ __align__(16) float M8_s[64];        // step-0 only
  __shared__ __align__(16) float C8_s[64];
  __shared__ __align__(16) float tk_s[S_];        // Mc^T k_t
  __shared__ __align__(16) float mf_s[L_];
  __shared__ __align__(16) float qv_s[L_];
  __shared__ __align__(16) float qsv_s[L_];
  __shared__ __align__(16) float q0v_s[L_];

  const int tid = threadIdx.x;
  const int lam = tid & 63;
  const int w   = tid >> 6;
  const int b   = blockIdx.x;
  const int mtl = w >> 2, ntl = w & 3;      // MFMA tile coords (P1)
  const int cc  = lam & 15, gg = lam >> 4;  // MFMA lane coords

  const float q_r  = qp[lam];
  const float qs_r = sqrtf(q_r);
  const float q0_r = q0p[lam];
  const float m0_r = m0p[lam];
  if (tid < 64) { qv_s[tid] = q_r; qsv_s[tid] = qs_r; q0v_s[tid] = q0_r; }

  // ---- A^T fragments (static) ----
  short8 ABh[2], ABl[2];
  {
    const float* arow = Ap + (size_t)(ntl*16 + cc)*64;
#pragma unroll
    for (int kk = 0; kk < 2; ++kk)
      ldfragF(arow + kk*32 + gg*8, ABh[kk], ABl[kk]);
  }

  float Kreg[8];
  {
    const float* kb = Kp + (size_t)b*(L_*R_) + lam*R_;
    float4 ka = *(const float4*)kb, kb4 = *(const float4*)(kb+4);
    Kreg[0]=ka.x;Kreg[1]=ka.y;Kreg[2]=ka.z;Kreg[3]=ka.w;
    Kreg[4]=kb4.x;Kreg[5]=kb4.y;Kreg[6]=kb4.z;Kreg[7]=kb4.w;
  }
  float kt_r = kp[(size_t)b*L_ + lam];

  // ---- prologue async loads ----
  if (w == 0) {                       // wp1[0] -> wp1b[1]
#pragma unroll
    for (int m = 0; m < 4; ++m) {
      int f = m*256 + lam*4, s = f >> 5, c = f & 31;
      gload16(wp1p + ((size_t)s*B_ + b)*S_ + c, &wp1b[1][f]);
    }
  } else if (w == 1 || w == 2) {      // wp2[0] -> wp2b[1]
#pragma unroll
    for (int m = 0; m < 4; ++m) {
      int f = (w-1)*1024 + m*256 + lam*4, s = f >> 6, c = f & 63;
      gload16(wp2p + ((size_t)s*B_ + b)*L_ + c, &wp2b[1][f]);
    }
  } else if (w == 3) {                // wf0 -> wfb[0] ; K[0] -> Ktb[0]
    { int f = lam*4, s = f >> 3, c = f & 7;
      gload16(wf0p + ((size_t)s*B_ + b)*R_ + c, &wfb[0][f]); }
#pragma unroll
    for (int m = 0; m < 2; ++m) {
      int f = m*256 + lam*4;
      gload16(Kp + (size_t)b*(L_*R_) + f, &Ktb[0][f]);
    }
  } else if (w == 4 || w == 5) {      // w_p0 -> wp2b[0]
#pragma unroll
    for (int m = 0; m < 4; ++m) {
      int f = (w-4)*1024 + m*256 + lam*4, s = f >> 6, c = f & 63;
      gload16(wp0p + ((size_t)s*B_ + b)*L_ + c, &wp2b[0][f]);
    }
  } else if (w == 6) {                // K[1] -> Ktb[1]
#pragma unroll
    for (int m = 0; m < 2; ++m) {
      int f = m*256 + lam*4;
      gload16(Kp + ((size_t)1*B_ + b)*(L_*R_) + f, &Ktb[1][f]);
    }
  } else if (w == 7) {                // wf[0] -> wfb[1] (for step 1)
    int f = lam*4, s = f >> 3, c = f & 7;
    gload16(wfp + ((size_t)s*B_ + b)*R_ + c, &wfb[1][f]);
  }
  __syncthreads();

  // 8x8 SPD: C8_s -> M8_s = inv(C8) via in-register Cholesky (step 0 only)
  auto chol8M8 = [&]() {
    const int i8 = lam & 7;
    float c8[8], rd8 = 0.0f;
#pragma unroll
    for (int k = 0; k < 8; ++k) c8[k] = C8_s[i8*8 + k];
#pragma unroll
    for (int j = 0; j < 8; ++j) {
      float dj = rdlane(c8[j], j);
      float rinv = rsqrtf(dj);
      if (i8 == j) rd8 = rinv;
      c8[j] *= rinv;
#pragma unroll
      for (int k = j+1; k < 8; ++k)
        c8[k] = fmaf(-rdlane(c8[j], k), c8[j], c8[k]);
    }
    float w8[8];
#pragma unroll
    for (int i = 0; i < 8; ++i) {
      float sacc = (i == i8) ? 1.0f : 0.0f;
#pragma unroll
      for (int k = 0; k < i; ++k)
        sacc = fmaf(-rdlane(c8[k], i), w8[k], sacc);
      w8[i] = sacc * rdlane(rd8, i);
    }
#pragma unroll
    for (int i = 0; i < 8; ++i) {
      float msum = 0.0f;
#pragma unroll
      for (int k = 0; k < 8; ++k)
        msum = fmaf(rdlane(w8[k], i), w8[k], msum);
      if (lam < 8) M8_s[i*8 + lam] = msum;
    }
  };

  // ================= step 0 =================
  {
    const float Pp = q0_r;
    const float h0 = m0_r / Pp + kt_r;
    if (w == 0) {
      const int r1 = lam >> 3, r2 = lam & 7;
      float acc = 0.0f;
#pragma unroll 4
      for (int l = 0; l < 64; ++l)
        acc = fmaf(Ktb[0][l*8 + r1] * q0v_s[l], Ktb[0][l*8 + r2], acc);
      C8_s[lam] = acc + (r1 == r2 ? 1.0f : 0.0f);
      chol8M8();
      float t8[8];
#pragma unroll
      for (int r = 0; r < 8; ++r) t8[r] = wsum(Pp * Kreg[r] * h0);
      float acc2 = 0.0f;
#pragma unroll
      for (int r1i = 0; r1i < 8; ++r1i) {
        float4 ma = *(const float4*)&M8_s[r1i*8];
        float4 mb = *(const float4*)&M8_s[r1i*8+4];
        float y = ma.x*t8[0]+ma.y*t8[1]+ma.z*t8[2]+ma.w*t8[3]
                + mb.x*t8[4]+mb.y*t8[5]+mb.z*t8[6]+mb.w*t8[7];
        acc2 = fmaf(Kreg[r1i], y, acc2);
      }
      float m0f = Pp*h0 - Pp*acc2;
      mf_s[lam] = m0f;
      outp[(size_t)b*L_ + lam] = m0f;
    }
    __syncthreads();

    const float qs0 = sqrtf(q0_r);
#pragma unroll
    for (int i = 0; i < 4; ++i) {
      const int s = 4*w + i;
      float zp = qs0 * wp2b[0][s*64 + lam];
      float v1[8];
#pragma unroll
      for (int r = 0; r < 8; ++r)
        v1[r] = wsum(Kreg[r] * zp) + wfb[0][s*8 + r];
      float acc = 0.0f;
#pragma unroll
      for (int r1i = 0; r1i < 8; ++r1i) {
        float4 ma = *(const float4*)&M8_s[r1i*8];
        float4 mb = *(const float4*)&M8_s[r1i*8+4];
        float y = ma.x*v1[0]+ma.y*v1[1]+ma.z*v1[2]+ma.w*v1[3]
                + mb.x*v1[4]+mb.y*v1[5]+mb.z*v1[6]+mb.w*v1[7];
        acc = fmaf(Kreg[r1i], y, acc);
      }
      z_s[s*68 + lam] = zp - Pp*acc;   // z' excludes m_f (added in next dyn)
    }
  }
  __syncthreads();

  // ================= steps 1..T-1 =================
  for (int t = 1; t < T_; ++t) {
    const int cb = t & 1, nb = cb ^ 1;

    // per-lane K/k reload (global; used P3b/P4)
    {
      const float* kb = Kp + ((size_t)t*B_ + b)*(L_*R_) + lam*R_;
      float4 ka = *(const float4*)kb, kb4 = *(const float4*)(kb+4);
      Kreg[0]=ka.x;Kreg[1]=ka.y;Kreg[2]=ka.z;Kreg[3]=ka.w;
      Kreg[4]=kb4.x;Kreg[5]=kb4.y;Kreg[6]=kb4.z;Kreg[7]=kb4.w;
      kt_r = kp[((size_t)t*B_ + b)*L_ + lam];
    }
    if (w == 0) ktv_s[lam] = kt_r;

    // ---- P1 (MFMA): X = (z'+mf) @ A^T ; zn = (z'+mf) + 0.1*tanh(X) ----
    {
      f32x4 acc = {0.0f, 0.0f, 0.0f, 0.0f};
#pragma unroll
      for (int kk = 0; kk < 2; ++kk) {
        const int l0 = kk*32 + gg*8;
        const int row = mtl*16 + cc;
        float4 za = *(const float4*)&z_s[row*68 + l0];
        float4 zb = *(const float4*)&z_s[row*68 + l0 + 4];
        float4 ma4 = *(const float4*)&mf_s[l0];
        float4 mb4 = *(const float4*)&mf_s[l0 + 4];
        float z8[8] = {za.x+ma4.x, za.y+ma4.y, za.z+ma4.z, za.w+ma4.w,
                       zb.x+mb4.x, zb.y+mb4.y, zb.z+mb4.z, zb.w+mb4.w};
        short8 ah, al;
        fsplit(z8, ah, al);
        acc = __builtin_amdgcn_mfma_f32_16x16x32_bf16(ah, ABh[kk], acc, 0, 0, 0);
        acc = __builtin_amdgcn_mfma_f32_16x16x32_bf16(al, ABh[kk], acc, 0, 0, 0);
        acc = __builtin_amdgcn_mfma_f32_16x16x32_bf16(ah, ABl[kk], acc, 0, 0, 0);
      }
      const int lout = ntl*16 + cc;
      const float mfl = mf_s[lout];
      float psum = 0.0f;
#pragma unroll
      for (int r = 0; r < 4; ++r) {
        const int sr = mtl*16 + gg*4 + r;
        float x = acc[r];
        float e = __expf(2.0f*x);
        float tnh = 1.0f - 2.0f/(e + 1.0f);
        float zv = (z_s[sr*68 + lout] + mfl) + 0.1f*tnh;
        zn_s[sr*68 + lout] = zv;
        psum += zv;
      }
      uni[(mtl*4 + gg)*68 + lout] = psum;
    }
    bar_lgkm();  // B1

    // ---- P2: m_p, Mc fp32 + bf16 staging (both layouts), KtT (w5) ----
    float mp = 0.0f;
#pragma unroll
    for (int ww = 0; ww < 8; ++ww) mp += uni[ww*68 + lam];
    mp *= 0.03125f;
    {
      short h4[4], l4[4];
#pragma unroll
      for (int i = 0; i < 4; ++i) {
        const int s = 4*w + i;
        float mcv = (zn_s[s*68 + lam] - mp) * 0.17677669529663689f;
        Mc_s[lam*36 + s] = mcv;
        uint32_t u = __float_as_uint(mcv);
        short hs = (short)(u >> 16);
        float hf = __uint_as_float(u & 0xFFFF0000u);
        short ls = (short)(__float_as_uint(mcv - hf) >> 16);
        h4[i] = hs; l4[i] = ls;
        McTH_s[s*72 + lam] = hs;
        McTL_s[s*72 + lam] = ls;
      }
      uint32_t hp0 = (uint32_t)(uint16_t)h4[0] | ((uint32_t)(uint16_t)h4[1] << 16);
      uint32_t hp1 = (uint32_t)(uint16_t)h4[2] | ((uint32_t)(uint16_t)h4[3] << 16);
      uint32_t lp0 = (uint32_t)(uint16_t)l4[0] | ((uint32_t)(uint16_t)l4[1] << 16);
      uint32_t lp1 = (uint32_t)(uint16_t)l4[2] | ((uint32_t)(uint16_t)l4[3] << 16);
      *(uint2*)&McH_s[lam*40 + 4*w] = make_uint2(hp0, hp1);
      *(uint2*)&McL_s[lam*40 + 4*w] = make_uint2(lp0, lp1);
    }
    if (w == 5) {   // KtT fp32 + bf16 hi/lo: KtT[r][l] = Ktb[cb][l][r]
      float4 a = *(const float4*)&Ktb[cb][lam*8];
      float4 c4 = *(const float4*)&Ktb[cb][lam*8+4];
      float kv[8] = {a.x,a.y,a.z,a.w,c4.x,c4.y,c4.z,c4.w};
#pragma unroll
      for (int r = 0; r < 8; ++r) {
        KtT_s[r*68 + lam] = kv[r];
        uint32_t u = __float_as_uint(kv[r]);
        short hs = (short)(u >> 16);
        float hf = __uint_as_float(u & 0xFFFF0000u);
        short ls = (short)(__float_as_uint(kv[r] - hf) >> 16);
        KtTH_s[r*72 + lam] = hs;
        KtTL_s[r*72 + lam] = ls;
      }
    }
    bar_lgkm();  // B2 (LDS only)

    // ---- P0': async prefetch for step t+1 (fenced at B4) ----
    if (t < T_-1) {
      if (w == 0) {
#pragma unroll
        for (int m = 0; m < 4; ++m) {
          int f = m*256 + lam*4, s = f >> 5, c = f & 31;
          gload16(wp1p + (((size_t)t*S_ + s)*B_ + b)*S_ + c, &wp1b[nb][f]);
        }
      } else if (w == 1 || w == 2) {
#pragma unroll
        for (int m = 0; m < 4; ++m) {
          int f = (w-1)*1024 + m*256 + lam*4, s = f >> 6, c = f & 63;
          gload16(wp2p + (((size_t)t*S_ + s)*B_ + b)*L_ + c, &wp2b[nb][f]);
        }
      } else if (w == 3) {
        { int f = lam*4, s = f >> 3, c = f & 7;
          gload16(wfp + (((size_t)t*S_ + s)*B_ + b)*R_ + c, &wfb[nb][f]); }
#pragma unroll
        for (int m = 0; m < 2; ++m) {
          int f = m*256 + lam*4;
          gload16(Kp + ((size_t)(t+1)*B_ + b)*(L_*R_) + f, &Ktb[nb][f]);
        }
      }
    }

    // ---- P3a: zp tiles (w2-7) + KM|tk tiles (w0-1, + KMT staging) ----
    if (w >= 2) {
      auto zpTile = [&](int tl) {
        const int mt = tl >> 2, nt = tl & 3;
        short8 ah, al;
        ldfragF(&wp1b[cb][(mt*16+cc)*32 + gg*8], ah, al);
        short8 bh = *(const short8*)&McH_s[(nt*16+cc)*40 + gg*8];
        short8 bl = *(const short8*)&McL_s[(nt*16+cc)*40 + gg*8];
        f32x4 acc = {0,0,0,0};
        acc = mfma3(ah, al, bh, bl, acc);
        const int col = nt*16 + cc;
        const float qsc = qsv_s[col];
#pragma unroll
        for (int r = 0; r < 4; ++r) {
          const int row = mt*16 + gg*4 + r;
          zn_s[row*68 + col] = acc[r] + qsc * wp2b[cb][row*64 + col];
        }
      };
      if (w <= 5) zpTile(w - 2);
      else { zpTile(2*w - 8); zpTile(2*w - 7); }   // w6:{4,5} w7:{6,7}
    } else {
      // [KM | tk][s][c] = sum_l Mc[l][s] * [K[l][c] | kt[l]]
      const int mt = w;
      f32x4 acc = {0,0,0,0};
#pragma unroll
      for (int ks = 0; ks < 2; ++ks) {
        short8 ah = *(const short8*)&McTH_s[(mt*16+cc)*72 + ks*32 + gg*8];
        short8 al = *(const short8*)&McTL_s[(mt*16+cc)*72 + ks*32 + gg*8];
        short8 bh, bl;
        if (cc < 8) {
          bh = *(const short8*)&KtTH_s[cc*72 + ks*32 + gg*8];
          bl = *(const short8*)&KtTL_s[cc*72 + ks*32 + gg*8];
        } else if (cc == 8) {
          float bv[8];
#pragma unroll
          for (int j = 0; j < 8; ++j) bv[j] = ktv_s[ks*32 + gg*8 + j];
          fsplit(bv, bh, bl);
        } else {
          bh = short8{0,0,0,0,0,0,0,0}; bl = short8{0,0,0,0,0,0,0,0};
        }
        acc = mfma3(ah, al, bh, bl, acc);
      }
#pragma unroll
      for (int r = 0; r < 4; ++r) {
        const int s = mt*16 + gg*4 + r;
        if (cc < 8) { KM_s[s*8 + cc] = acc[r]; KMT_s[cc*36 + s] = acc[r]; }
        else if (cc == 8) tk_s[s] = acc[r];
      }
    }
    bar_lgkm();  // B2b (zp, KM, KMT, tk visible)

    // ---- P3b: v1t (w2-3), W8 solve (w1), u+t8 (w0) ----
    float u_r = 0.0f, t8s[8];
#pragma unroll
    for (int r = 0; r < 8; ++r) t8s[r] = 0.0f;
    if (w == 0) {
      float mctk = 0.0f;
#pragma unroll
      for (int s4 = 0; s4 < 32; s4 += 4) {
        float4 mc4 = *(const float4*)&Mc_s[lam*36 + s4];
        float4 tb  = *(const float4*)&tk_s[s4];
        mctk = fmaf(mc4.x, tb.x, mctk);
        mctk = fmaf(mc4.y, tb.y, mctk);
        mctk = fmaf(mc4.z, tb.z, mctk);
        mctk = fmaf(mc4.w, tb.w, mctk);
      }
      u_r = mp + mctk + q_r * kt_r;
#pragma unroll
      for (int r = 0; r < 8; ++r)
        t8s[r] = rdlane(wredsum(Kreg[r] * u_r), 63);
    } else if (w == 1) {
      // (a) C8 Gram -> C8_s
      const int r1 = lam >> 3, r2 = lam & 7;
      float acc = 0.0f;
#pragma unroll
      for (int s4 = 0; s4 < 32; s4 += 4) {     // KM-Gram via KMT b128 rows
        float4 ka = *(const float4*)&KMT_s[r1*36 + s4];
        float4 kb = *(const float4*)&KMT_s[r2*36 + s4];
        acc = fmaf(ka.x, kb.x, acc);
        acc = fmaf(ka.y, kb.y, acc);
        acc = fmaf(ka.z, kb.z, acc);
        acc = fmaf(ka.w, kb.w, acc);
      }
#pragma unroll 4
      for (int l4 = 0; l4 < 64; l4 += 4) {     // q-Gram via KtT b128 rows
        float4 ka = *(const float4*)&KtT_s[r1*68 + l4];
        float4 kb = *(const float4*)&KtT_s[r2*68 + l4];
        float4 qv4 = *(const float4*)&qv_s[l4];
        acc = fmaf(ka.x*qv4.x, kb.x, acc);
        acc = fmaf(ka.y*qv4.y, kb.y, acc);
        acc = fmaf(ka.z*qv4.z, kb.z, acc);
        acc = fmaf(ka.w*qv4.w, kb.w, acc);
      }
      C8_s[lam] = acc + (r1 == r2 ? 1.0f : 0.0f);
      // (b) mkm[r] = sum_s Mc[lam][s]*KM[s][r] (hides C8_s write latency)
      float mkm[8];
#pragma unroll
      for (int r = 0; r < 8; ++r) mkm[r] = 0.0f;
#pragma unroll
      for (int s4 = 0; s4 < 32; s4 += 4) {
        float4 mc4 = *(const float4*)&Mc_s[lam*36 + s4];
#pragma unroll
        for (int ii = 0; ii < 4; ++ii) {
          const float mcl = (ii==0)?mc4.x:(ii==1)?mc4.y:(ii==2)?mc4.z:mc4.w;
          float4 ka = *(const float4*)&KM_s[(s4+ii)*8];
          float4 kb = *(const float4*)&KM_s[(s4+ii)*8+4];
          mkm[0] = fmaf(mcl, ka.x, mkm[0]);
          mkm[1] = fmaf(mcl, ka.y, mkm[1]);
          mkm[2] = fmaf(mcl, ka.z, mkm[2]);
          mkm[3] = fmaf(mcl, ka.w, mkm[3]);
          mkm[4] = fmaf(mcl, kb.x, mkm[4]);
          mkm[5] = fmaf(mcl, kb.y, mkm[5]);
          mkm[6] = fmaf(mcl, kb.z, mkm[6]);
          mkm[7] = fmaf(mcl, kb.w, mkm[7]);
        }
      }
      // (c) Cholesky FACTOR (lanes i8=lam&7 hold rows; c8[j] = col j -> L[:,j])
      {
        const int i8 = lam & 7;
        float c8[8], rd8 = 0.0f;
#pragma unroll
        for (int k = 0; k < 8; ++k) c8[k] = C8_s[i8*8 + k];
#pragma unroll
        for (int j = 0; j < 8; ++j) {
          float dj = rdlane(c8[j], j);
          float rinv = rsqrtf(dj);
          if (i8 == j) rd8 = rinv;
          c8[j] *= rinv;
#pragma unroll
          for (int k = j+1; k < 8; ++k)
            c8[k] = fmaf(-rdlane(c8[j], k), c8[j], c8[k]);
        }
        // (d) per-lane solve C8 x = n, n = mkm + q*K  (L[j][k] = rdlane(c8[k], j))
        float n8[8];
#pragma unroll
        for (int r = 0; r < 8; ++r) n8[r] = fmaf(q_r, Kreg[r], mkm[r]);
        float y8[8];
#pragma unroll
        for (int j = 0; j < 8; ++j) {          // L y = n
          float a = n8[j];
#pragma unroll
          for (int k = 0; k < 8; ++k) if (k < j)
            a = fmaf(-rdlane(c8[k], j), y8[k], a);
          y8[j] = a * rdlane(rd8, j);
        }
        float x8[8];
#pragma unroll
        for (int j = 7; j >= 0; --j) {         // L^T x = y
          float a = y8[j];
#pragma unroll
          for (int k = 7; k >= 0; --k) if (k > j)
            a = fmaf(-rdlane(c8[j], k), x8[k], a);
          x8[j] = a * rdlane(rd8, j);
        }
        *(float4*)&W8_s[lam*8]   = make_float4(x8[0], x8[1], x8[2], x8[3]);
        *(float4*)&W8_s[lam*8+4] = make_float4(x8[4], x8[5], x8[6], x8[7]);
      }
    } else if (w == 2 || w == 3) {
      // v1t[s][r] = sum_l zp[s][l]*K[l][r] + wf
      const int mt = w - 2;
      f32x4 acc = {0,0,0,0};
#pragma unroll
      for (int ks = 0; ks < 2; ++ks) {
        short8 ah, al;
        ldfragF(&zn_s[(mt*16+cc)*68 + ks*32 + gg*8], ah, al);
        short8 bh, bl;
        if (cc < 8) {
          bh = *(const short8*)&KtTH_s[cc*72 + ks*32 + gg*8];
          bl = *(const short8*)&KtTL_s[cc*72 + ks*32 + gg*8];
        } else {
          bh = short8{0,0,0,0,0,0,0,0}; bl = short8{0,0,0,0,0,0,0,0};
        }
        acc = mfma3(ah, al, bh, bl, acc);
      }
#pragma unroll
      for (int r = 0; r < 4; ++r) {
        const int s = mt*16 + gg*4 + r;
        if (cc < 8) v1t_s[s*8 + cc] = acc[r] + wfb[cb][s*8 + cc];
      }
    }
    bar_lgkm();  // B3 (W8_s, v1t_s visible)

    // ---- P4: z -= v1t . W8[lam]; w0: mf = u - t8 . W8[lam] ----
    {
      float4 wa = *(const float4*)&W8_s[lam*8];
      float4 wb = *(const float4*)&W8_s[lam*8+4];
#pragma unroll
      for (int i = 0; i < 4; ++i) {
        const int s = 4*w + i;
        float4 va = *(const float4*)&v1t_s[s*8];
        float4 vb = *(const float4*)&v1t_s[s*8+4];
        float zc = wa.x*va.x + wa.y*va.y + wa.z*va.z + wa.w*va.w
                 + wb.x*vb.x + wb.y*vb.y + wb.z*vb.z + wb.w*vb.w;
        z_s[s*68 + lam] = zn_s[s*68 + lam] - zc;   // z' (mf added next dyn)
      }
      if (w == 0) {
        float mc = wa.x*t8s[0] + wa.y*t8s[1] + wa.z*t8s[2] + wa.w*t8s[3]
                 + wb.x*t8s[4] + wb.y*t8s[5] + wb.z*t8s[6] + wb.w*t8s[7];
        const float mf_r = u_r - mc;
        mf_s[lam] = mf_r;
        outp[((size_t)t*B_ + b)*L_ + lam] = mf_r;
      }
    }
    barV();  // B4 (mf_s, z_s visible; fences this step's prefetches)
  }
}

extern "C" void kernel_launch(void* const* d_in, const int* in_sizes, int n_in,
                              void* d_out, int out_size, void* d_ws, size_t ws_size,
                              hipStream_t stream) {
  (void)in_sizes; (void)n_in; (void)out_size; (void)d_ws; (void)ws_size;
  nlf_kernel<<<dim3(B_), dim3(512), 0, stream>>>(
      (const float*)d_in[0], (const float*)d_in[1], (const float*)d_in[2],
      (const float*)d_in[3], (const float*)d_in[4], (const float*)d_in[5],
      (const float*)d_in[6], (const float*)d_in[7], (const float*)d_in[8],
      (const float*)d_in[9], (const float*)d_in[10], (float*)d_out);
}